// Round 5
// baseline (151.737 us; speedup 1.0000x reference)
//
#include <hip/hip_runtime.h>

// DotMatrix, ell-fused, packed-LDS: out[b,i,j, ell*32+tau, c] = complex dot over m
//   a = rep_ell[b,i,tau,:,:],  w[m] = rep_ell[b,j,tau,2ell-m,:] * (-1)^(m-ell)
// Write-bound: 134 MB out, 2 MB in. Per (it,f) LDS group packs all 4 ells
// contiguously -> 16x ds_read_b128 per iter; j-fragments float4-loaded with
// flip/sign folded into compile-time fma signs.

namespace {

typedef float f32x4 __attribute__((ext_vector_type(4)));

constexpr int Bn = 2;
constexpr int Nn = 256;
constexpr int TI = 8;    // i' rows per block
constexpr int TJ = 16;   // j' cols per block
constexpr int FSTR = 68; // floats per (it,f) LDS group: 64 data + 4 pad (272 B)
constexpr int LDSF = TI * 16 * FSTR;  // 8704 floats = 34 KB

__host__ __device__ constexpr int doff(int ell) {  // ell segment offset in group
  return ell == 0 ? 0 : ell == 1 ? 4 : ell == 2 ? 16 : 36;
}

// Stage A-tile for one ell into packed LDS layout. Source reads are
// consecutive float4s (fully coalesced); dest stride 272 B (<=2-way banks).
template <int ELL>
__device__ __forceinline__ void stage_ell(const float* __restrict__ rep,
                                          float* __restrict__ lds,
                                          int b, int i0, int tid) {
  constexpr int M = 2 * ELL + 1;
  constexpr int ROWF4 = 16 * M;        // float4s per (b,i) row (all 32 taus)
  constexpr int TOT = TI * ROWF4;
  const f32x4* base = reinterpret_cast<const f32x4*>(rep + (size_t)(b * Nn + i0) * (64 * M));
  for (int x = tid; x < TOT; x += 256) {
    const int it  = x / ROWF4;
    const int idx = x - it * ROWF4;    // float4 index within row = f*M + c
    const int f   = idx / M;
    const int c   = idx - f * M;
    const f32x4 v = base[x];
    *reinterpret_cast<f32x4*>(lds + (it * 16 + f) * FSTR + doff(ELL) + 4 * c) = v;
  }
}

// Raw j-fragment (2 taus = 2f,2f+1) as M float4 loads into scalar regs.
template <int ELL>
__device__ __forceinline__ void load_rb(const float* __restrict__ rep, int b, int jg,
                                        int f, float (&rb)[4 * (2 * ELL + 1)]) {
  constexpr int M = 2 * ELL + 1;
  const f32x4* g = reinterpret_cast<const f32x4*>(rep + (size_t)(b * Nn + jg) * (64 * M)) + M * f;
  #pragma unroll
  for (int k = 0; k < M; ++k) {
    const f32x4 v = g[k];
    rb[4 * k + 0] = v.x; rb[4 * k + 1] = v.y; rb[4 * k + 2] = v.z; rb[4 * k + 3] = v.w;
  }
}

// Complex dot for 2 taus at one (ell, i'): A from packed LDS (b128 reads),
// flip + (-1)^(m-ell) folded into compile-time fma signs.
template <int ELL>
__device__ __forceinline__ f32x4 dot2(const float* __restrict__ la,
                                      const float (&rb)[4 * (2 * ELL + 1)]) {
  constexpr int M = 2 * ELL + 1;
  float ra[4 * M];
  #pragma unroll
  for (int k = 0; k < M; ++k) {
    const f32x4 v = *reinterpret_cast<const f32x4*>(la + 4 * k);
    ra[4 * k + 0] = v.x; ra[4 * k + 1] = v.y; ra[4 * k + 2] = v.z; ra[4 * k + 3] = v.w;
  }
  float d[4];
  #pragma unroll
  for (int t = 0; t < 2; ++t) {
    float dr = 0.0f, di = 0.0f;
    #pragma unroll
    for (int m = 0; m < M; ++m) {
      const float ar = ra[t * 2 * M + 2 * m + 0];
      const float ai = ra[t * 2 * M + 2 * m + 1];
      const float wr = rb[t * 2 * M + (2 * ELL - m) * 2 + 0];
      const float wi = rb[t * 2 * M + (2 * ELL - m) * 2 + 1];
      if (((m ^ ELL) & 1) == 0) {
        dr = fmaf(ar, wr, dr); dr = fmaf(-ai, wi, dr);
        di = fmaf(ar, wi, di); di = fmaf(ai, wr, di);
      } else {
        dr = fmaf(-ar, wr, dr); dr = fmaf(ai, wi, dr);
        di = fmaf(-ar, wi, di); di = fmaf(-ai, wr, di);
      }
    }
    d[2 * t + 0] = dr; d[2 * t + 1] = di;
  }
  f32x4 v; v.x = d[0]; v.y = d[1]; v.z = d[2]; v.w = d[3];
  return v;
}

__global__ __launch_bounds__(256) void dotmat_kernel(
    const float* __restrict__ r0, const float* __restrict__ r1,
    const float* __restrict__ r2, const float* __restrict__ r3,
    float* __restrict__ out) {
  __shared__ __align__(16) float lds[LDSF];
  const int b   = blockIdx.z;
  const int i0  = blockIdx.y * TI;
  const int j0  = blockIdx.x * TJ;
  const int tid = threadIdx.x;

  stage_ell<0>(r0, lds, b, i0, tid);
  stage_ell<1>(r1, lds, b, i0, tid);
  stage_ell<2>(r2, lds, b, i0, tid);
  stage_ell<3>(r3, lds, b, i0, tid);

  const int f  = tid & 15;   // tau-pair / float4 slot within 64-float segment
  const int jj = tid >> 4;   // j'

  float rb0[4], rb1[12], rb2[20], rb3[28];
  load_rb<0>(r0, b, j0 + jj, f, rb0);
  load_rb<1>(r1, b, j0 + jj, f, rb1);
  load_rb<2>(r2, b, j0 + jj, f, rb2);
  load_rb<3>(r3, b, j0 + jj, f, rb3);

  __syncthreads();

  for (int it = 0; it < TI; ++it) {
    const float* lag = lds + (it * 16 + f) * FSTR;
    float* op = out + (size_t)((b * Nn + i0 + it) * Nn + (j0 + jj)) * 256 + f * 4;
    const f32x4 v0 = dot2<0>(lag + doff(0), rb0);
    const f32x4 v1 = dot2<1>(lag + doff(1), rb1);
    const f32x4 v2 = dot2<2>(lag + doff(2), rb2);
    const f32x4 v3 = dot2<3>(lag + doff(3), rb3);
    __builtin_nontemporal_store(v0, reinterpret_cast<f32x4*>(op + 0 * 64));
    __builtin_nontemporal_store(v1, reinterpret_cast<f32x4*>(op + 1 * 64));
    __builtin_nontemporal_store(v2, reinterpret_cast<f32x4*>(op + 2 * 64));
    __builtin_nontemporal_store(v3, reinterpret_cast<f32x4*>(op + 3 * 64));
  }
}

}  // namespace

extern "C" void kernel_launch(void* const* d_in, const int* in_sizes, int n_in,
                              void* d_out, int out_size, void* d_ws, size_t ws_size,
                              hipStream_t stream) {
  (void)in_sizes; (void)n_in; (void)out_size; (void)d_ws; (void)ws_size;
  const float* r0 = (const float*)d_in[0];
  const float* r1 = (const float*)d_in[1];
  const float* r2 = (const float*)d_in[2];
  const float* r3 = (const float*)d_in[3];
  float* out = (float*)d_out;
  dim3 grid(Nn / TJ, Nn / TI, Bn);  // (16, 32, 2) = 1024 blocks
  dotmat_kernel<<<grid, 256, 0, stream>>>(r0, r1, r2, r3, out);
}

// Round 7
// 148.656 us; speedup vs baseline: 1.0207x; 1.0207x over previous
//
#include <hip/hip_runtime.h>

// DotMatrix, ell-fused, packed-LDS, PLAIN stores (A/B vs R5's nontemporal):
//   out[b,i,j, ell*32+tau, c] = complex dot over m of
//   a = rep_ell[b,i,tau,:,:],  w[m] = rep_ell[b,j,tau,2ell-m,:] * (-1)^(m-ell)
// Write-bound: 134 MB out, 2 MB in.

namespace {

typedef float f32x4 __attribute__((ext_vector_type(4)));

constexpr int Bn = 2;
constexpr int Nn = 256;
constexpr int TI = 8;    // i' rows per block
constexpr int TJ = 16;   // j' cols per block
constexpr int FSTR = 68; // floats per (it,f) LDS group: 64 data + 4 pad (272 B)
constexpr int LDSF = TI * 16 * FSTR;  // 8704 floats = 34 KB

__host__ __device__ constexpr int doff(int ell) {  // ell segment offset in group
  return ell == 0 ? 0 : ell == 1 ? 4 : ell == 2 ? 16 : 36;
}

// Stage A-tile for one ell into packed LDS layout. Source reads are
// consecutive float4s (fully coalesced); dest stride 272 B (<=2-way banks).
template <int ELL>
__device__ __forceinline__ void stage_ell(const float* __restrict__ rep,
                                          float* __restrict__ lds,
                                          int b, int i0, int tid) {
  constexpr int M = 2 * ELL + 1;
  constexpr int ROWF4 = 16 * M;        // float4s per (b,i) row (all 32 taus)
  constexpr int TOT = TI * ROWF4;
  const f32x4* base = reinterpret_cast<const f32x4*>(rep + (size_t)(b * Nn + i0) * (64 * M));
  for (int x = tid; x < TOT; x += 256) {
    const int it  = x / ROWF4;
    const int idx = x - it * ROWF4;    // float4 index within row = f*M + c
    const int f   = idx / M;
    const int c   = idx - f * M;
    const f32x4 v = base[x];
    *reinterpret_cast<f32x4*>(lds + (it * 16 + f) * FSTR + doff(ELL) + 4 * c) = v;
  }
}

// Raw j-fragment (2 taus = 2f,2f+1) as M float4 loads into scalar regs.
template <int ELL>
__device__ __forceinline__ void load_rb(const float* __restrict__ rep, int b, int jg,
                                        int f, float (&rb)[4 * (2 * ELL + 1)]) {
  constexpr int M = 2 * ELL + 1;
  const f32x4* g = reinterpret_cast<const f32x4*>(rep + (size_t)(b * Nn + jg) * (64 * M)) + M * f;
  #pragma unroll
  for (int k = 0; k < M; ++k) {
    const f32x4 v = g[k];
    rb[4 * k + 0] = v.x; rb[4 * k + 1] = v.y; rb[4 * k + 2] = v.z; rb[4 * k + 3] = v.w;
  }
}

// Complex dot for 2 taus at one (ell, i'): A from packed LDS (b128 reads),
// flip + (-1)^(m-ell) folded into compile-time fma signs.
template <int ELL>
__device__ __forceinline__ f32x4 dot2(const float* __restrict__ la,
                                      const float (&rb)[4 * (2 * ELL + 1)]) {
  constexpr int M = 2 * ELL + 1;
  float ra[4 * M];
  #pragma unroll
  for (int k = 0; k < M; ++k) {
    const f32x4 v = *reinterpret_cast<const f32x4*>(la + 4 * k);
    ra[4 * k + 0] = v.x; ra[4 * k + 1] = v.y; ra[4 * k + 2] = v.z; ra[4 * k + 3] = v.w;
  }
  float d[4];
  #pragma unroll
  for (int t = 0; t < 2; ++t) {
    float dr = 0.0f, di = 0.0f;
    #pragma unroll
    for (int m = 0; m < M; ++m) {
      const float ar = ra[t * 2 * M + 2 * m + 0];
      const float ai = ra[t * 2 * M + 2 * m + 1];
      const float wr = rb[t * 2 * M + (2 * ELL - m) * 2 + 0];
      const float wi = rb[t * 2 * M + (2 * ELL - m) * 2 + 1];
      if (((m ^ ELL) & 1) == 0) {
        dr = fmaf(ar, wr, dr); dr = fmaf(-ai, wi, dr);
        di = fmaf(ar, wi, di); di = fmaf(ai, wr, di);
      } else {
        dr = fmaf(-ar, wr, dr); dr = fmaf(ai, wi, dr);
        di = fmaf(-ar, wi, di); di = fmaf(-ai, wr, di);
      }
    }
    d[2 * t + 0] = dr; d[2 * t + 1] = di;
  }
  f32x4 v; v.x = d[0]; v.y = d[1]; v.z = d[2]; v.w = d[3];
  return v;
}

__global__ __launch_bounds__(256) void dotmat_kernel(
    const float* __restrict__ r0, const float* __restrict__ r1,
    const float* __restrict__ r2, const float* __restrict__ r3,
    float* __restrict__ out) {
  __shared__ __align__(16) float lds[LDSF];
  const int b   = blockIdx.z;
  const int i0  = blockIdx.y * TI;
  const int j0  = blockIdx.x * TJ;
  const int tid = threadIdx.x;

  stage_ell<0>(r0, lds, b, i0, tid);
  stage_ell<1>(r1, lds, b, i0, tid);
  stage_ell<2>(r2, lds, b, i0, tid);
  stage_ell<3>(r3, lds, b, i0, tid);

  const int f  = tid & 15;   // tau-pair / float4 slot within 64-float segment
  const int jj = tid >> 4;   // j'

  float rb0[4], rb1[12], rb2[20], rb3[28];
  load_rb<0>(r0, b, j0 + jj, f, rb0);
  load_rb<1>(r1, b, j0 + jj, f, rb1);
  load_rb<2>(r2, b, j0 + jj, f, rb2);
  load_rb<3>(r3, b, j0 + jj, f, rb3);

  __syncthreads();

  for (int it = 0; it < TI; ++it) {
    const float* lag = lds + (it * 16 + f) * FSTR;
    float* op = out + (size_t)((b * Nn + i0 + it) * Nn + (j0 + jj)) * 256 + f * 4;
    const f32x4 v0 = dot2<0>(lag + doff(0), rb0);
    const f32x4 v1 = dot2<1>(lag + doff(1), rb1);
    const f32x4 v2 = dot2<2>(lag + doff(2), rb2);
    const f32x4 v3 = dot2<3>(lag + doff(3), rb3);
    *reinterpret_cast<f32x4*>(op + 0 * 64) = v0;
    *reinterpret_cast<f32x4*>(op + 1 * 64) = v1;
    *reinterpret_cast<f32x4*>(op + 2 * 64) = v2;
    *reinterpret_cast<f32x4*>(op + 3 * 64) = v3;
  }
}

}  // namespace

extern "C" void kernel_launch(void* const* d_in, const int* in_sizes, int n_in,
                              void* d_out, int out_size, void* d_ws, size_t ws_size,
                              hipStream_t stream) {
  (void)in_sizes; (void)n_in; (void)out_size; (void)d_ws; (void)ws_size;
  const float* r0 = (const float*)d_in[0];
  const float* r1 = (const float*)d_in[1];
  const float* r2 = (const float*)d_in[2];
  const float* r3 = (const float*)d_in[3];
  float* out = (float*)d_out;
  dim3 grid(Nn / TJ, Nn / TI, Bn);  // (16, 32, 2) = 1024 blocks
  dotmat_kernel<<<grid, 256, 0, stream>>>(r0, r1, r2, r3, out);
}